// Round 1
// baseline (45415.527 us; speedup 1.0000x reference)
//
#include <hip/hip_runtime.h>
#include <math.h>

// Elman RNN: batch=64, T=2048, in=256, hidden=512, out=256, fp32.
// Round 1: kernel-per-timestep pipeline (sequential dep over t), fp32 exact.
//   step t: blocks 0..63  -> h_{t+1} = tanh(h_t @ W1_h + x_t @ W1_x + b1)
//           blocks 64..95 -> y_{t-1} = h_t @ W2 + b2   (skipped at t=0)
//   final : y_{T-1} + h_last copy.
// ws: h double-buffer only (2 * 64*512 fp32 = 256 KB).

#define BB 64
#define TT 2048
#define II 256
#define HH 512
#define OO 256
#define OUT_OFF ((size_t)BB * TT * OO) // h_last offset in d_out (33554432)

__global__ void rnn_init_h(float* __restrict__ hbuf) {
    int idx = blockIdx.x * blockDim.x + threadIdx.x; // 64*512 threads
    hbuf[idx] = 0.0f;
}

// 512 threads: tj = tid&63 (column), tb = (tid>>6)&3 (batch sub), kh = tid>>8 (k split)
// Each thread accumulates 2 batch rows (b0, b0+4) for one output column.
__global__ __launch_bounds__(512, 1) void rnn_step(
    const float* __restrict__ x, const float* __restrict__ W1,
    const float* __restrict__ bias1, const float* __restrict__ W2,
    const float* __restrict__ bias2, const float* __restrict__ hprev,
    float* __restrict__ hnext, float* __restrict__ out, int t)
{
    __shared__ float sm0[512];
    __shared__ float sm1[512];
    const int tid = threadIdx.x;
    const int blk = blockIdx.x;

    if (blk < 64) {
        // ---- A: h update ----
        const int jt = blk & 7, bt = blk >> 3;
        const int tj = tid & 63, tb = (tid >> 6) & 3, kh = tid >> 8;
        const int j  = jt * 64 + tj;
        const int b0 = bt * 8 + tb, b1i = b0 + 4;
        float a0 = 0.f, a1 = 0.f;
        if (kh == 0) {
            // hidden part: k = 0..511 over W1 rows [0,512)
            const float* h0 = hprev + b0  * HH;
            const float* h1 = hprev + b1i * HH;
            const float* w  = W1 + j;
            #pragma unroll 8
            for (int k = 0; k < HH; ++k) {
                float wv = w[(size_t)k * HH];
                a0 = fmaf(h0[k], wv, a0);
                a1 = fmaf(h1[k], wv, a1);
            }
        } else {
            // input part: i = 0..255 over W1 rows [512,768)
            const float* x0 = x + ((size_t)b0  * TT + t) * II;
            const float* x1 = x + ((size_t)b1i * TT + t) * II;
            const float* w  = W1 + (size_t)HH * HH + j;
            #pragma unroll 8
            for (int k = 0; k < II; ++k) {
                float wv = w[(size_t)k * HH];
                a0 = fmaf(x0[k], wv, a0);
                a1 = fmaf(x1[k], wv, a1);
            }
        }
        sm0[tid] = a0; sm1[tid] = a1;
        __syncthreads();
        if (tid < 256) {
            float s0 = sm0[tid] + sm0[tid + 256] + bias1[j];
            float s1 = sm1[tid] + sm1[tid + 256] + bias1[j];
            hnext[(size_t)b0  * HH + j] = tanhf(s0);
            hnext[(size_t)b1i * HH + j] = tanhf(s1);
        }
    } else {
        // ---- B: y_{t-1} from h_t ----
        if (t == 0) return;
        const int blk2 = blk - 64;
        const int ot = blk2 & 3, bt = blk2 >> 2;
        const int to = tid & 63, tb = (tid >> 6) & 3, kh = tid >> 8;
        const int o  = ot * 64 + to;
        const int b0 = bt * 8 + tb, b1i = b0 + 4;
        float a0 = 0.f, a1 = 0.f;
        const float* h0 = hprev + (size_t)b0  * HH + kh * 256;
        const float* h1 = hprev + (size_t)b1i * HH + kh * 256;
        const float* w  = W2 + (size_t)(kh * 256) * OO + o;
        #pragma unroll 8
        for (int k = 0; k < 256; ++k) {
            float wv = w[(size_t)k * OO];
            a0 = fmaf(h0[k], wv, a0);
            a1 = fmaf(h1[k], wv, a1);
        }
        sm0[tid] = a0; sm1[tid] = a1;
        __syncthreads();
        if (tid < 256) {
            float s0 = sm0[tid] + sm0[tid + 256] + bias2[o];
            float s1 = sm1[tid] + sm1[tid + 256] + bias2[o];
            out[((size_t)b0  * TT + (t - 1)) * OO + o] = s0;
            out[((size_t)b1i * TT + (t - 1)) * OO + o] = s1;
        }
    }
}

// blocks 0..31: y_{T-1}; blocks 32..39: copy h_last (64*512) to d_out tail
__global__ __launch_bounds__(512, 1) void rnn_final(
    const float* __restrict__ hfin, const float* __restrict__ W2,
    const float* __restrict__ bias2, float* __restrict__ out)
{
    __shared__ float sm0[512];
    __shared__ float sm1[512];
    const int tid = threadIdx.x;
    const int blk = blockIdx.x;
    if (blk < 32) {
        const int ot = blk & 3, bt = blk >> 2;
        const int to = tid & 63, tb = (tid >> 6) & 3, kh = tid >> 8;
        const int o  = ot * 64 + to;
        const int b0 = bt * 8 + tb, b1i = b0 + 4;
        float a0 = 0.f, a1 = 0.f;
        const float* h0 = hfin + (size_t)b0  * HH + kh * 256;
        const float* h1 = hfin + (size_t)b1i * HH + kh * 256;
        const float* w  = W2 + (size_t)(kh * 256) * OO + o;
        #pragma unroll 8
        for (int k = 0; k < 256; ++k) {
            float wv = w[(size_t)k * OO];
            a0 = fmaf(h0[k], wv, a0);
            a1 = fmaf(h1[k], wv, a1);
        }
        sm0[tid] = a0; sm1[tid] = a1;
        __syncthreads();
        if (tid < 256) {
            float s0 = sm0[tid] + sm0[tid + 256] + bias2[o];
            float s1 = sm1[tid] + sm1[tid + 256] + bias2[o];
            out[((size_t)b0  * TT + (TT - 1)) * OO + o] = s0;
            out[((size_t)b1i * TT + (TT - 1)) * OO + o] = s1;
        }
    } else {
        // h_last: 64*512 = 32768 floats, 8 blocks * 512 threads * 8 each
        const int idx = (blk - 32) * 512 + tid;
        #pragma unroll
        for (int m = 0; m < 8; ++m) {
            int p = m * 4096 + idx;
            out[OUT_OFF + p] = hfin[p];
        }
    }
}

extern "C" void kernel_launch(void* const* d_in, const int* in_sizes, int n_in,
                              void* d_out, int out_size, void* d_ws, size_t ws_size,
                              hipStream_t stream) {
    const float* x  = (const float*)d_in[0];
    const float* W1 = (const float*)d_in[1];
    const float* b1 = (const float*)d_in[2];
    const float* W2 = (const float*)d_in[3];
    const float* b2 = (const float*)d_in[4];
    float* out  = (float*)d_out;
    float* hbuf = (float*)d_ws; // [2][BB*HH] double buffer

    rnn_init_h<<<dim3(64), dim3(512), 0, stream>>>(hbuf);
    for (int t = 0; t < TT; ++t) {
        float* hp = hbuf + (size_t)(t & 1) * (BB * HH);
        float* hn = hbuf + (size_t)((t + 1) & 1) * (BB * HH);
        rnn_step<<<dim3(96), dim3(512), 0, stream>>>(x, W1, b1, W2, b2, hp, hn, out, t);
    }
    // after t=2047, final h lives in hbuf[(2048)&1] == hbuf[0]
    rnn_final<<<dim3(40), dim3(512), 0, stream>>>(hbuf, W2, b2, out);
}